// Round 15
// baseline (686.480 us; speedup 1.0000x reference)
//
#include <hip/hip_runtime.h>

#define B 8
#define NOBJ 128
#define NATTR 4
#define T 12
#define MC 2048
#define E 128
#define IDD 64
#define AD 64
#define HD 256
#define C 2176

typedef short s16x8 __attribute__((ext_vector_type(8)));
typedef float f32x4 __attribute__((ext_vector_type(4)));

__device__ inline unsigned short f2b(float f) {
  union { float f; unsigned u; } v; v.f = f;
  unsigned r = v.u + 0x7FFFu + ((v.u >> 16) & 1u);
  return (unsigned short)(r >> 16);
}
__device__ inline float b2f(unsigned short u) {
  union { unsigned u; float f; } v; v.u = ((unsigned)u) << 16;
  return v.f;
}

// coherent (MALL-routed) accessors: WRITES + flags only; fresh buffers are
// PLAIN-read after flag gating (validated R10-R13)
__device__ __forceinline__ void st_coh_u64(unsigned long long* p, unsigned long long v) {
  __hip_atomic_store(p, v, __ATOMIC_RELAXED, __HIP_MEMORY_SCOPE_AGENT);
}
__device__ __forceinline__ void st_coh_u32(unsigned* p, unsigned v) {
  __hip_atomic_store(p, v, __ATOMIC_RELAXED, __HIP_MEMORY_SCOPE_AGENT);
}
__device__ __forceinline__ void st_coh_f32(float* p, float v) {
  union { float f; unsigned u; } c; c.f = v;
  __hip_atomic_store((unsigned*)p, c.u, __ATOMIC_RELAXED, __HIP_MEMORY_SCOPE_AGENT);
}
__device__ __forceinline__ unsigned ld_coh_u32(const unsigned* p) {
  return __hip_atomic_load(p, __ATOMIC_RELAXED, __HIP_MEMORY_SCOPE_AGENT);
}

// LDS swizzles: XOR row bits into the 16B-slot index (conflict-free b128)
__device__ __forceinline__ int gidx(int r, int c) {   // g [64][128]
  return r * 128 + ((((c >> 3) ^ (r & 15)) << 3) | (c & 7));
}
__device__ __forceinline__ int hidx(int r, int c) {   // h [64][256]
  return r * 256 + ((((c >> 3) ^ (r & 15)) << 3) | (c & 7));
}
__device__ __forceinline__ int mtidx(int r, int c) {  // mt [128][128]
  return r * 128 + ((((c >> 3) ^ (r & 15)) << 3) | (c & 7));
}

// ---------------- setup A (no LDS): dendron build + weight cvt/transpose + flags ----
__global__ __launch_bounds__(256) void k_setupA(
    const int* __restrict__ scene,
    const float* __restrict__ aein,
    const float* __restrict__ cein,
    const float* __restrict__ aw1, const float* __restrict__ aw2,
    const float* __restrict__ mw1, const float* __restrict__ mw2,
    unsigned short* __restrict__ dendron_bf,
    unsigned short* __restrict__ w1_bf, unsigned short* __restrict__ w2_bf,
    float* __restrict__ mw1T, float* __restrict__ mw2T,
    unsigned* __restrict__ flags) {
  int blk = blockIdx.x;
  int tid = threadIdx.x;
  if (blk < 4352) {
    int gid = blk * 2 + (tid >> 7);
    int e = tid & 127;
    int b = gid / C, j = gid % C;
    float din;
    if (j < MC) {
      din = cein[j * E + e];
    } else {
      int obj = j - MC;
      float sIn = 0.f;
      for (int a = 0; a < NATTR; a++) {
        int s = scene[(b * NOBJ + obj) * NATTR + a];
        float m = (s != -1) ? 1.f : 0.f;
        sIn += aein[(s + 1) * E + e] * m;
      }
      din = sIn;
    }
    dendron_bf[(size_t)gid * E + e] = f2b(din);
  } else if (blk < 4544) {
    int i = (blk - 4352) * 256 + tid;
    if (i < HD * E)  w1_bf[i] = f2b(aw1[i]);
    if (i < AD * HD) w2_bf[i] = f2b(aw2[i]);
    if (i < 192 * HD) { int c = i / HD, k = i % HD; mw1T[c * HD + k] = mw1[k * 192 + c]; }
    if (i < HD * AD)  { int k = i / AD, a = i % AD; mw2T[k * AD + a] = mw2[a * HD + k]; }
  } else {
    for (int i = tid; i < 1024; i += 256) flags[i] = 0u;
  }
}

// ---------------- setup B (LDS): transA/idT/siaT/att_g/proj + meta ----------------
__global__ __launch_bounds__(256) void k_setupB(
    const int* __restrict__ scene,
    const float* __restrict__ aeout, const float* __restrict__ aeid,
    const float* __restrict__ ceout, const float* __restrict__ ceid,
    const float* __restrict__ att_init,
    const int* __restrict__ prog_op, const int* __restrict__ prog_arg,
    const float* __restrict__ mw1T, const float* __restrict__ mb1,
    const float* __restrict__ mw2T, const float* __restrict__ mb2,
    unsigned short* __restrict__ axonT, unsigned short* __restrict__ idT_g,
    unsigned short* __restrict__ siaT, float* __restrict__ att_g,
    float* __restrict__ meta_all, float* __restrict__ proj_all) {
  int blk = blockIdx.x;
  int tid = threadIdx.x;
  __shared__ float sbuf[13952];   // 55.8 KB carve
  if (blk < 272) {
    int b = blk / 34, jc = blk % 34;
    int j0 = jc * 64;
    float* ax   = sbuf;                 // [64][129]
    float* idb  = sbuf + 64 * 129;      // [64][65]
    float* argL = idb + 64 * 65;        // [12][128]
    int lane = tid & 63, lr = lane & 15;
    float s = att_init[lane];
    s += __shfl_xor(s, 1, 64);  s += __shfl_xor(s, 2, 64);
    s += __shfl_xor(s, 4, 64);  s += __shfl_xor(s, 8, 64);
    s += __shfl_xor(s, 16, 64); s += __shfl_xor(s, 32, 64);
    float am0 = s * (1.f / AD);
    for (int i = tid; i < 64 * 128; i += 256) {
      int j = i >> 7, e = i & 127;
      int jg = j0 + j;
      float v;
      if (jg < MC) v = ceout[jg * E + e];
      else {
        int obj = jg - MC;
        v = 0.f;
        for (int a = 0; a < NATTR; a++) {
          int sc = scene[(b * NOBJ + obj) * NATTR + a];
          float m = (sc != -1) ? 1.f : 0.f;
          v += aeout[(sc + 1) * E + e] * m;
        }
      }
      ax[j * 129 + e] = v;
    }
    for (int i = tid; i < 64 * 64; i += 256) {
      int j = i >> 6, d = i & 63;
      int jg = j0 + j;
      float v;
      if (jg < MC) v = ceid[jg * IDD + d];
      else {
        int obj = jg - MC;
        v = 0.f;
        for (int a = 0; a < NATTR; a++) {
          int sc = scene[(b * NOBJ + obj) * NATTR + a];
          float m = (sc != -1) ? 1.f : 0.f;
          v += aeid[(sc + 1) * IDD + d] * m;
        }
      }
      idb[j * 65 + d] = v;
    }
    for (int i = tid; i < T * 128; i += 256) {
      int t = i >> 7, e = i & 127;
      int arg = prog_arg[b * T + t];
      argL[t * 128 + e] = ceout[arg * E + e];
    }
    __syncthreads();
    for (int i = tid; i < 128 * 64; i += 256) {
      int e = i >> 6, jj = i & 63;
      axonT[(size_t)(b * E + e) * C + j0 + jj] = f2b(ax[jj * 129 + e]);
    }
    for (int i = tid; i < 64 * 64; i += 256) {
      int d = i >> 6, jj = i & 63;
      idT_g[(size_t)(b * 64 + d) * C + j0 + jj] = f2b(idb[jj * 65 + d]);
      siaT[(size_t)(b * 128 + d) * C + j0 + jj] = f2b(idb[jj * 65 + d] * am0);
      siaT[(size_t)(b * 128 + 64 + d) * C + j0 + jj] = f2b(att_init[d] * am0);
    }
    {
      float* ag = att_g + (size_t)blk * 4096 + tid * 16;
      #pragma unroll
      for (int n = 0; n < 4; n++) {
        float v0 = att_init[n * 16 + lr];
        #pragma unroll
        for (int v = 0; v < 4; v++) ag[n * 4 + v] = v0;
      }
    }
    // proj: dot(argL[t], ax[jj]) / E for this block's 64 rows
    {
      int jj = tid & 63, tq = tid >> 6;
      #pragma unroll
      for (int sI = 0; sI < 3; sI++) {
        int t = tq + 4 * sI;
        const float* ar = argL + t * 128;
        const float* axr = ax + jj * 129;
        float acc = 0.f;
        #pragma unroll 8
        for (int e = 0; e < 128; e++) acc += axr[e] * ar[e];
        proj_all[((size_t)t * B + b) * C + j0 + jj] = acc * (1.f / E);
      }
    }
  } else {
    // meta scan (coalesced transposed weights)
    int b = blk - 272;
    float* x = sbuf;            // [192]
    float* h = sbuf + 192;      // [256]
    float* meta = h + 256;      // [64]
    if (tid < AD) meta[tid] = att_init[tid];
    __syncthreads();
    for (int t = 0; t < T; t++) {
      int arg = prog_arg[b * T + t];
      if (tid < AD) x[tid] = meta[tid];
      else if (tid < 192) x[tid] = ceout[arg * E + (tid - 64)];
      __syncthreads();
      float s = mb1[tid];
      for (int c = 0; c < 192; c++) s += x[c] * mw1T[c * HD + tid];
      h[tid] = fmaxf(s, 0.f);
      __syncthreads();
      if (tid < AD) {
        float o = mb2[tid];
        for (int k = 0; k < HD; k++) o += h[k] * mw2T[k * AD + tid];
        float m = (prog_op[b * T + t] == 0) ? 1.f : 0.f;
        float nm = m * o + (1.f - m) * meta[tid];
        meta[tid] = nm;
        meta_all[(t * B + b) * AD + tid] = nm;
      }
      __syncthreads();
    }
  }
}

// ---------------- fused per-step kernel (R13 + 32 producers + afr hoist) ----
__global__ __launch_bounds__(256) void k_step(
    int t,
    const unsigned short* __restrict__ dendron_bf,
    const unsigned short* __restrict__ axonT,
    const unsigned short* __restrict__ idT_g,
    const unsigned short* __restrict__ siaT_in,
    const unsigned short* __restrict__ w1_bf, const float* __restrict__ b1g,
    const unsigned short* __restrict__ w2_bf, const float* __restrict__ b2g,
    const float* __restrict__ proj_all, const float* __restrict__ meta_all,
    const int* __restrict__ prog_op,
    unsigned long long* __restrict__ Mt64,
    float* __restrict__ att_g, unsigned short* __restrict__ siaT_out,
    float* __restrict__ rowmean, float* __restrict__ out,
    float* __restrict__ att_hist, float* __restrict__ ins_hist,
    float* __restrict__ trans_hist,
    unsigned* __restrict__ mflag, unsigned* __restrict__ sflag) {
  const int blk = blockIdx.x;
  const int b = blk / 34, ch = blk % 34, j0 = ch * 64;
  const int tid = threadIdx.x;
  const int w = tid >> 6, lane = tid & 63, lr = lane & 15, lg = lane >> 4;

  __shared__ unsigned short smem[24576];           // 48 KB overlay
  __shared__ float am_l[64];
  __shared__ float red[256];
  unsigned short* g_l = smem;                      // bytes [0,16K)
  unsigned short* mt  = smem + 8192;               // bytes [16K,48K)
  unsigned short* h_l = smem + 8192;
  float* mred = (float*)smem;                      // producer scratch [4][16][33]

  const f32x4 z = {0.f, 0.f, 0.f, 0.f};
  const unsigned ph = (unsigned)(t + 1);

  // loads independent of M, hoisted above the producer/poll section
  float att[4][4];
  {
    const f32x4* ag = (const f32x4*)(att_g + (size_t)blk * 4096 + tid * 16);
    #pragma unroll
    for (int n = 0; n < 4; n++) {
      f32x4 v4 = ag[n];
      #pragma unroll
      for (int v = 0; v < 4; v++) att[n][v] = v4[v];
    }
  }
  s16x8 afr[4];
  #pragma unroll
  for (int ke = 0; ke < 4; ke++)
    afr[ke] = *(const s16x8*)(dendron_bf + (size_t)(b * C + j0 + w * 16 + lr) * E + ke * 32 + lg * 8);

  // ---- producers: ch<32 compute one 16x32 tile of M = siaT @ axonT^T ----
  if (ch < 32) {
    int d0 = (ch >> 2) * 16, e0 = (ch & 3) * 32;
    const unsigned short* ap0 = siaT_in + (size_t)(b * 128 + d0 + lr) * C + w * 544 + lg * 8;
    const unsigned short* bp0 = axonT + (size_t)(b * E + e0 + lr) * C + w * 544 + lg * 8;
    const unsigned short* bp1 = bp0 + (size_t)16 * C;
    f32x4 a00 = z, a01 = z;
    #pragma unroll 4
    for (int kk = 0; kk < 17; kk++) {
      int k0 = kk * 32;
      s16x8 A0 = *(const s16x8*)(ap0 + k0);
      s16x8 B0 = *(const s16x8*)(bp0 + k0);
      s16x8 B1 = *(const s16x8*)(bp1 + k0);
      a00 = __builtin_amdgcn_mfma_f32_16x16x32_bf16(A0, B0, a00, 0, 0, 0);
      a01 = __builtin_amdgcn_mfma_f32_16x16x32_bf16(A0, B1, a01, 0, 0, 0);
    }
    // partials -> LDS [4][16][33]
    #pragma unroll
    for (int v = 0; v < 4; v++) {
      mred[(w * 16 + lg * 4 + v) * 33 + lr]      = a00[v];
      mred[(w * 16 + lg * 4 + v) * 33 + 16 + lr] = a01[v];
    }
    __syncthreads();
    if (tid < 128) {
      int r = tid >> 3, c = (tid & 7) * 4;
      float s0 = 0.f, s1 = 0.f, s2 = 0.f, s3 = 0.f;
      #pragma unroll
      for (int w4 = 0; w4 < 4; w4++) {
        const float* p = &mred[(w4 * 16 + r) * 33 + c];
        s0 += p[0]; s1 += p[1]; s2 += p[2]; s3 += p[3];
      }
      unsigned long long pk = (unsigned long long)f2b(s0)
                            | ((unsigned long long)f2b(s1) << 16)
                            | ((unsigned long long)f2b(s2) << 32)
                            | ((unsigned long long)f2b(s3) << 48);
      st_coh_u64(Mt64 + (((size_t)(b * 128 + d0 + r) * 128) + e0 + c) / 4, pk);
    }
    asm volatile("s_waitcnt vmcnt(0)" ::: "memory");
    __syncthreads();
    if (tid == 0) st_coh_u32(mflag + b * 32 + ch, ph);
  }
  // ---- all blocks: wait for this batch's 32 M-tiles ----
  if (tid < 32) {
    while (ld_coh_u32(mflag + b * 32 + tid) < ph) __builtin_amdgcn_s_sleep(1);
  }
  __syncthreads();
  // ---- stage Mt -> LDS (PLAIN cached loads) ----
  {
    const unsigned long long* mtp = Mt64 + (size_t)b * 4096;
    #pragma unroll
    for (int k = 0; k < 16; k++) {
      int idx = tid + k * 256;
      unsigned long long v = mtp[idx];
      int r = idx >> 5, c4 = (idx & 31) * 4;
      *(unsigned long long*)&mt[mtidx(r, c4)] = v;
    }
  }
  __syncthreads();
  // ---- phase A: g = dendron @ M / C ----
  {
    #pragma unroll
    for (int n = 0; n < 8; n++) {
      f32x4 acc = z;
      #pragma unroll
      for (int ke = 0; ke < 4; ke++) {
        s16x8 bf = *(const s16x8*)&mt[mtidx(n * 16 + lr, ke * 32 + lg * 8)];
        acc = __builtin_amdgcn_mfma_f32_16x16x32_bf16(afr[ke], bf, acc, 0, 0, 0);
      }
      #pragma unroll
      for (int v = 0; v < 4; v++)
        g_l[gidx(w * 16 + lg * 4 + v, n * 16 + lr)] = f2b(acc[v] * (1.f / C));
    }
  }
  __syncthreads();
  // ---- phase B: h = relu(g @ w1^T + b1) ----
  {
    s16x8 gf[4];
    #pragma unroll
    for (int kd = 0; kd < 4; kd++)
      gf[kd] = *(const s16x8*)&g_l[gidx(w * 16 + lr, kd * 32 + lg * 8)];
    #pragma unroll
    for (int n = 0; n < 16; n++) {
      f32x4 acc = z;
      #pragma unroll
      for (int kd = 0; kd < 4; kd++) {
        s16x8 bf = *(const s16x8*)(w1_bf + (size_t)(n * 16 + lr) * E + kd * 32 + lg * 8);
        acc = __builtin_amdgcn_mfma_f32_16x16x32_bf16(gf[kd], bf, acc, 0, 0, 0);
      }
      float b1v = b1g[n * 16 + lr];
      #pragma unroll
      for (int v = 0; v < 4; v++)
        h_l[hidx(w * 16 + lg * 4 + v, n * 16 + lr)] = f2b(fmaxf(acc[v] + b1v, 0.f));
    }
  }
  __syncthreads();
  // ---- phase C: out = h @ w2^T ; update att ; hist ----
  {
    s16x8 hf[8];
    #pragma unroll
    for (int kk = 0; kk < 8; kk++)
      hf[kk] = *(const s16x8*)&h_l[hidx(w * 16 + lr, kk * 32 + lg * 8)];
    int op = prog_op[b * T + t];
    float insF = (op == 1) ? 1.f : 0.f, trF = (op == 2) ? 1.f : 0.f;
    float projv[4];
    #pragma unroll
    for (int v = 0; v < 4; v++)
      projv[v] = proj_all[(size_t)(t * B + b) * C + j0 + w * 16 + lg * 4 + v];
    #pragma unroll
    for (int n = 0; n < 4; n++) {
      f32x4 acc = z;
      #pragma unroll
      for (int kk = 0; kk < 8; kk++) {
        s16x8 bf = *(const s16x8*)(w2_bf + (size_t)(n * 16 + lr) * HD + kk * 32 + lg * 8);
        acc = __builtin_amdgcn_mfma_f32_16x16x32_bf16(hf[kk], bf, acc, 0, 0, 0);
      }
      int a = n * 16 + lr;
      float b2v = b2g[a];
      float meta_a = meta_all[(size_t)(t * B + b) * AD + a];
      #pragma unroll
      for (int v = 0; v < 4; v++) {
        int row = lg * 4 + v;
        int i = j0 + w * 16 + row;
        float transfer = acc[v] + b2v + b2f(g_l[gidx(w * 16 + row, 64 + a)]);
        float insert = meta_a * projv[v];
        float attv = att[n][v] + insF * insert + trF * transfer;
        attv = (attv >= 0.f) ? attv : 0.01f * attv;
        attv = fminf(fmaxf(attv, -1.f), 2.f);
        att[n][v] = attv;
        size_t hi = (((size_t)t * B + b) * C + i) * AD + a;
        __builtin_nontemporal_store(attv, att_hist + hi);
        __builtin_nontemporal_store(insert, ins_hist + hi);
        __builtin_nontemporal_store(transfer, trans_hist + hi);
      }
    }
  }
  // ---- epilogue: amean ----
  float amr[4];
  {
    float s[4];
    #pragma unroll
    for (int v = 0; v < 4; v++) s[v] = att[0][v] + att[1][v] + att[2][v] + att[3][v];
    #pragma unroll
    for (int v = 0; v < 4; v++) {
      s[v] += __shfl_xor(s[v], 1, 64);
      s[v] += __shfl_xor(s[v], 2, 64);
      s[v] += __shfl_xor(s[v], 4, 64);
      s[v] += __shfl_xor(s[v], 8, 64);
      amr[v] = s[v] * (1.f / AD);
    }
    if (lr == 0) {
      #pragma unroll
      for (int v = 0; v < 4; v++) am_l[w * 16 + lg * 4 + v] = amr[v];
    }
  }
  if (t < T - 1) {
    // persist att state + att-half of next siaT (plain; boundary coherence)
    {
      f32x4* ag = (f32x4*)(att_g + (size_t)blk * 4096 + tid * 16);
      #pragma unroll
      for (int n = 0; n < 4; n++) {
        f32x4 v4;
        #pragma unroll
        for (int v = 0; v < 4; v++) v4[v] = att[n][v];
        ag[n] = v4;
        unsigned long long pk = 0;
        #pragma unroll
        for (int v = 0; v < 4; v++)
          pk |= (unsigned long long)f2b(att[n][v] * amr[v]) << (16 * v);
        *(unsigned long long*)(siaT_out + (size_t)(b * 128 + 64 + n * 16 + lr) * C + j0 + w * 16 + lg * 4) = pk;
      }
    }
    __syncthreads();   // am_l ready
    // id half of next siaT
    #pragma unroll
    for (int k2 = 0; k2 < 2; k2++) {
      int idx = tid + k2 * 256;
      int d = idx >> 3, part = idx & 7;
      int j = part * 8;
      s16x8 iv = *(const s16x8*)(idT_g + (size_t)(b * 64 + d) * C + j0 + j);
      s16x8 ov;
      #pragma unroll
      for (int m = 0; m < 8; m++)
        ov[m] = (short)f2b(b2f((unsigned short)iv[m]) * am_l[j + m]);
      *(s16x8*)(siaT_out + (size_t)(b * 128 + d) * C + j0 + j) = ov;
    }
  } else {
    // ---- last step: rowmean (coherent) + sflag + per-batch softmax tail ----
    if (lr == 0) {
      #pragma unroll
      for (int v = 0; v < 4; v++)
        st_coh_f32(rowmean + (size_t)b * C + j0 + w * 16 + lg * 4 + v, amr[v]);
    }
    asm volatile("s_waitcnt vmcnt(0)" ::: "memory");
    __syncthreads();
    if (tid == 0) st_coh_u32(sflag + b * 34 + ch, 1u);
    if (ch == 0) {
      if (tid < 34) {
        while (ld_coh_u32(sflag + b * 34 + tid) < 1u) __builtin_amdgcn_s_sleep(1);
      }
      __syncthreads();
      float* am = (float*)smem;
      for (int i = tid; i < C; i += 256) am[i] = rowmean[(size_t)b * C + i];
      __syncthreads();
      float mx = -1e30f;
      for (int i = tid; i < C; i += 256) mx = fmaxf(mx, am[i]);
      red[tid] = mx; __syncthreads();
      for (int s2 = 128; s2 > 0; s2 >>= 1) { if (tid < s2) red[tid] = fmaxf(red[tid], red[tid + s2]); __syncthreads(); }
      mx = red[0]; __syncthreads();
      float sm = 0.f;
      for (int i = tid; i < C; i += 256) sm += expf(am[i] - mx);
      red[tid] = sm; __syncthreads();
      for (int s2 = 128; s2 > 0; s2 >>= 1) { if (tid < s2) red[tid] += red[tid + s2]; __syncthreads(); }
      float lse = logf(red[0]) + mx;
      for (int i = tid; i < C; i += 256) out[(size_t)b * C + i] = am[i] - lse;
    }
  }
}

extern "C" void kernel_launch(void* const* d_in, const int* in_sizes, int n_in,
                              void* d_out, int out_size, void* d_ws, size_t ws_size,
                              hipStream_t stream) {
  const int* scene     = (const int*)d_in[0];
  const int* prog_op   = (const int*)d_in[1];
  const int* prog_arg  = (const int*)d_in[2];
  const float* aein    = (const float*)d_in[3];
  const float* aeout   = (const float*)d_in[4];
  const float* aeid    = (const float*)d_in[5];
  const float* cein    = (const float*)d_in[6];
  const float* ceout   = (const float*)d_in[7];
  const float* ceid    = (const float*)d_in[8];
  const float* att_init = (const float*)d_in[11];
  const float* aw1 = (const float*)d_in[12];
  const float* ab1 = (const float*)d_in[13];
  const float* aw2 = (const float*)d_in[14];
  const float* ab2 = (const float*)d_in[15];
  const float* mw1 = (const float*)d_in[16];
  const float* mb1 = (const float*)d_in[17];
  const float* mw2 = (const float*)d_in[18];
  const float* mb2 = (const float*)d_in[19];

  char* ws = (char*)d_ws;
  size_t off = 0;
  auto carve = [&](size_t bytes) { char* p = ws + off; off += (bytes + 255) & ~(size_t)255; return p; };
  float* proj_all  = (float*)carve((size_t)T * B * C * 4);
  float* meta_all  = (float*)carve((size_t)T * B * AD * 4);
  float* mw1T      = (float*)carve((size_t)192 * HD * 4);
  float* mw2T      = (float*)carve((size_t)HD * AD * 4);
  float* rowmean   = (float*)carve((size_t)B * C * 4);
  float* att_g     = (float*)carve((size_t)272 * 4096 * 4);
  unsigned short* dendron_bf = (unsigned short*)carve((size_t)B * C * E * 2);
  unsigned short* axonT      = (unsigned short*)carve((size_t)B * E * C * 2);
  unsigned short* idT_g      = (unsigned short*)carve((size_t)B * 64 * C * 2);
  unsigned short* siaT       = (unsigned short*)carve((size_t)B * 128 * C * 2);
  unsigned long long* Mt64   = (unsigned long long*)carve((size_t)B * 4096 * 8);
  unsigned short* w1_bf      = (unsigned short*)carve((size_t)HD * E * 2);
  unsigned short* w2_bf      = (unsigned short*)carve((size_t)AD * HD * 2);
  unsigned*       flags      = (unsigned*)carve(4096);
  unsigned*       mflag = flags;            // [8][32]
  unsigned*       sflag = flags + 256;      // [8][34]

  float* out_sm     = (float*)d_out;
  float* att_hist   = out_sm + B * C;
  float* ins_hist   = att_hist + (size_t)T * B * C * AD;
  float* trans_hist = ins_hist + (size_t)T * B * C * AD;

  k_setupA<<<dim3(4545), dim3(256), 0, stream>>>(scene, aein, cein, aw1, aw2, mw1, mw2,
                                                 dendron_bf, w1_bf, w2_bf, mw1T, mw2T, flags);
  k_setupB<<<dim3(280), dim3(256), 0, stream>>>(scene, aeout, aeid, ceout, ceid, att_init,
                                                prog_op, prog_arg, mw1T, mb1, mw2T, mb2,
                                                axonT, idT_g, siaT, att_g,
                                                meta_all, proj_all);
  for (int t = 0; t < T; t++) {
    k_step<<<dim3(272), dim3(256), 0, stream>>>(t, dendron_bf, axonT, idT_g, siaT,
                                                w1_bf, ab1, w2_bf, ab2,
                                                proj_all, meta_all, prog_op,
                                                Mt64, att_g, siaT, rowmean, out_sm,
                                                att_hist, ins_hist, trans_hist,
                                                mflag, sflag);
  }
}

// Round 16
// 648.893 us; speedup vs baseline: 1.0579x; 1.0579x over previous
//
#include <hip/hip_runtime.h>

#define B 8
#define NOBJ 128
#define NATTR 4
#define T 12
#define MC 2048
#define E 128
#define IDD 64
#define AD 64
#define HD 256
#define C 2176

typedef short s16x8 __attribute__((ext_vector_type(8)));
typedef float f32x4 __attribute__((ext_vector_type(4)));

__device__ inline unsigned short f2b(float f) {
  union { float f; unsigned u; } v; v.f = f;
  unsigned r = v.u + 0x7FFFu + ((v.u >> 16) & 1u);
  return (unsigned short)(r >> 16);
}
__device__ inline float b2f(unsigned short u) {
  union { unsigned u; float f; } v; v.u = ((unsigned)u) << 16;
  return v.f;
}

// coherent (MALL-routed) accessors: WRITES + flags only; fresh buffers are
// PLAIN-read after flag gating (validated R10-R13)
__device__ __forceinline__ void st_coh_u64(unsigned long long* p, unsigned long long v) {
  __hip_atomic_store(p, v, __ATOMIC_RELAXED, __HIP_MEMORY_SCOPE_AGENT);
}
__device__ __forceinline__ void st_coh_u32(unsigned* p, unsigned v) {
  __hip_atomic_store(p, v, __ATOMIC_RELAXED, __HIP_MEMORY_SCOPE_AGENT);
}
__device__ __forceinline__ void st_coh_f32(float* p, float v) {
  union { float f; unsigned u; } c; c.f = v;
  __hip_atomic_store((unsigned*)p, c.u, __ATOMIC_RELAXED, __HIP_MEMORY_SCOPE_AGENT);
}
__device__ __forceinline__ unsigned ld_coh_u32(const unsigned* p) {
  return __hip_atomic_load(p, __ATOMIC_RELAXED, __HIP_MEMORY_SCOPE_AGENT);
}

// LDS swizzles: XOR row bits into the 16B-slot index (conflict-free b128)
__device__ __forceinline__ int gidx(int r, int c) {   // g [64][128]
  return r * 128 + ((((c >> 3) ^ (r & 15)) << 3) | (c & 7));
}
__device__ __forceinline__ int hidx(int r, int c) {   // h [64][256]
  return r * 256 + ((((c >> 3) ^ (r & 15)) << 3) | (c & 7));
}
__device__ __forceinline__ int mtidx(int r, int c) {  // mt [128][128]
  return r * 128 + ((((c >> 3) ^ (r & 15)) << 3) | (c & 7));
}

// ---------------- setup A (no LDS): dendron build + weight cvt/transpose + flags ----
__global__ __launch_bounds__(256) void k_setupA(
    const int* __restrict__ scene,
    const float* __restrict__ aein,
    const float* __restrict__ cein,
    const float* __restrict__ aw1, const float* __restrict__ aw2,
    const float* __restrict__ mw1, const float* __restrict__ mw2,
    unsigned short* __restrict__ dendron_bf,
    unsigned short* __restrict__ w1_bf, unsigned short* __restrict__ w2_bf,
    float* __restrict__ mw1T, float* __restrict__ mw2T,
    unsigned* __restrict__ flags) {
  int blk = blockIdx.x;
  int tid = threadIdx.x;
  if (blk < 4352) {
    int gid = blk * 2 + (tid >> 7);
    int e = tid & 127;
    int b = gid / C, j = gid % C;
    float din;
    if (j < MC) {
      din = cein[j * E + e];
    } else {
      int obj = j - MC;
      float sIn = 0.f;
      for (int a = 0; a < NATTR; a++) {
        int s = scene[(b * NOBJ + obj) * NATTR + a];
        float m = (s != -1) ? 1.f : 0.f;
        sIn += aein[(s + 1) * E + e] * m;
      }
      din = sIn;
    }
    dendron_bf[(size_t)gid * E + e] = f2b(din);
  } else if (blk < 4544) {
    int i = (blk - 4352) * 256 + tid;
    if (i < HD * E)  w1_bf[i] = f2b(aw1[i]);
    if (i < AD * HD) w2_bf[i] = f2b(aw2[i]);
    if (i < 192 * HD) { int c = i / HD, k = i % HD; mw1T[c * HD + k] = mw1[k * 192 + c]; }
    if (i < HD * AD)  { int k = i / AD, a = i % AD; mw2T[k * AD + a] = mw2[a * HD + k]; }
  } else {
    for (int i = tid; i < 512; i += 256) flags[i] = 0u;
  }
}

// ---------------- setup B (LDS): transA/idT/siaT/att_g/proj + meta ----------------
__global__ __launch_bounds__(256) void k_setupB(
    const int* __restrict__ scene,
    const float* __restrict__ aeout, const float* __restrict__ aeid,
    const float* __restrict__ ceout, const float* __restrict__ ceid,
    const float* __restrict__ att_init,
    const int* __restrict__ prog_op, const int* __restrict__ prog_arg,
    const float* __restrict__ mw1T, const float* __restrict__ mb1,
    const float* __restrict__ mw2T, const float* __restrict__ mb2,
    unsigned short* __restrict__ axonT, unsigned short* __restrict__ idT_g,
    unsigned short* __restrict__ siaT, float* __restrict__ att_g,
    float* __restrict__ meta_all, float* __restrict__ proj_all) {
  int blk = blockIdx.x;
  int tid = threadIdx.x;
  __shared__ float sbuf[13952];   // 55.8 KB carve
  if (blk < 272) {
    int b = blk / 34, jc = blk % 34;
    int j0 = jc * 64;
    float* ax   = sbuf;                 // [64][129]
    float* idb  = sbuf + 64 * 129;      // [64][65]
    float* argL = idb + 64 * 65;        // [12][128]
    int lane = tid & 63, lr = lane & 15;
    float s = att_init[lane];
    s += __shfl_xor(s, 1, 64);  s += __shfl_xor(s, 2, 64);
    s += __shfl_xor(s, 4, 64);  s += __shfl_xor(s, 8, 64);
    s += __shfl_xor(s, 16, 64); s += __shfl_xor(s, 32, 64);
    float am0 = s * (1.f / AD);
    for (int i = tid; i < 64 * 128; i += 256) {
      int j = i >> 7, e = i & 127;
      int jg = j0 + j;
      float v;
      if (jg < MC) v = ceout[jg * E + e];
      else {
        int obj = jg - MC;
        v = 0.f;
        for (int a = 0; a < NATTR; a++) {
          int sc = scene[(b * NOBJ + obj) * NATTR + a];
          float m = (sc != -1) ? 1.f : 0.f;
          v += aeout[(sc + 1) * E + e] * m;
        }
      }
      ax[j * 129 + e] = v;
    }
    for (int i = tid; i < 64 * 64; i += 256) {
      int j = i >> 6, d = i & 63;
      int jg = j0 + j;
      float v;
      if (jg < MC) v = ceid[jg * IDD + d];
      else {
        int obj = jg - MC;
        v = 0.f;
        for (int a = 0; a < NATTR; a++) {
          int sc = scene[(b * NOBJ + obj) * NATTR + a];
          float m = (sc != -1) ? 1.f : 0.f;
          v += aeid[(sc + 1) * IDD + d] * m;
        }
      }
      idb[j * 65 + d] = v;
    }
    for (int i = tid; i < T * 128; i += 256) {
      int t = i >> 7, e = i & 127;
      int arg = prog_arg[b * T + t];
      argL[t * 128 + e] = ceout[arg * E + e];
    }
    __syncthreads();
    for (int i = tid; i < 128 * 64; i += 256) {
      int e = i >> 6, jj = i & 63;
      axonT[(size_t)(b * E + e) * C + j0 + jj] = f2b(ax[jj * 129 + e]);
    }
    for (int i = tid; i < 64 * 64; i += 256) {
      int d = i >> 6, jj = i & 63;
      idT_g[(size_t)(b * 64 + d) * C + j0 + jj] = f2b(idb[jj * 65 + d]);
      siaT[(size_t)(b * 128 + d) * C + j0 + jj] = f2b(idb[jj * 65 + d] * am0);
      siaT[(size_t)(b * 128 + 64 + d) * C + j0 + jj] = f2b(att_init[d] * am0);
    }
    {
      float* ag = att_g + (size_t)blk * 4096 + tid * 16;
      #pragma unroll
      for (int n = 0; n < 4; n++) {
        float v0 = att_init[n * 16 + lr];
        #pragma unroll
        for (int v = 0; v < 4; v++) ag[n * 4 + v] = v0;
      }
    }
    // proj: dot(argL[t], ax[jj]) / E for this block's 64 rows
    {
      int jj = tid & 63, tq = tid >> 6;
      #pragma unroll
      for (int sI = 0; sI < 3; sI++) {
        int t = tq + 4 * sI;
        const float* ar = argL + t * 128;
        const float* axr = ax + jj * 129;
        float acc = 0.f;
        #pragma unroll 8
        for (int e = 0; e < 128; e++) acc += axr[e] * ar[e];
        proj_all[((size_t)t * B + b) * C + j0 + jj] = acc * (1.f / E);
      }
    }
  } else {
    // meta scan (coalesced transposed weights)
    int b = blk - 272;
    float* x = sbuf;            // [192]
    float* h = sbuf + 192;      // [256]
    float* meta = h + 256;      // [64]
    if (tid < AD) meta[tid] = att_init[tid];
    __syncthreads();
    for (int t = 0; t < T; t++) {
      int arg = prog_arg[b * T + t];
      if (tid < AD) x[tid] = meta[tid];
      else if (tid < 192) x[tid] = ceout[arg * E + (tid - 64)];
      __syncthreads();
      float s = mb1[tid];
      for (int c = 0; c < 192; c++) s += x[c] * mw1T[c * HD + tid];
      h[tid] = fmaxf(s, 0.f);
      __syncthreads();
      if (tid < AD) {
        float o = mb2[tid];
        for (int k = 0; k < HD; k++) o += h[k] * mw2T[k * AD + tid];
        float m = (prog_op[b * T + t] == 0) ? 1.f : 0.f;
        float nm = m * o + (1.f - m) * meta[tid];
        meta[tid] = nm;
        meta_all[(t * B + b) * AD + tid] = nm;
      }
      __syncthreads();
    }
  }
}

// ---------------- fused per-step kernel (R7, Mt staged PLAIN) ----------------
// blocks 34 per batch; ch<16 also produce one 32x32 M-tile first.
__global__ __launch_bounds__(256) void k_step(
    int t,
    const unsigned short* __restrict__ dendron_bf,
    const unsigned short* __restrict__ axonT,
    const unsigned short* __restrict__ idT_g,
    const unsigned short* __restrict__ siaT_in,
    const unsigned short* __restrict__ w1_bf, const float* __restrict__ b1g,
    const unsigned short* __restrict__ w2_bf, const float* __restrict__ b2g,
    const float* __restrict__ proj_all, const float* __restrict__ meta_all,
    const int* __restrict__ prog_op,
    unsigned long long* __restrict__ Mt64,
    float* __restrict__ att_g, unsigned short* __restrict__ siaT_out,
    float* __restrict__ rowmean, float* __restrict__ out,
    float* __restrict__ att_hist, float* __restrict__ ins_hist,
    float* __restrict__ trans_hist,
    unsigned* __restrict__ mflag, unsigned* __restrict__ sflag) {
  const int blk = blockIdx.x;
  const int b = blk / 34, ch = blk % 34, j0 = ch * 64;
  const int tid = threadIdx.x;
  const int w = tid >> 6, lane = tid & 63, lr = lane & 15, lg = lane >> 4;

  __shared__ unsigned short smem[24576];           // 48 KB overlay
  __shared__ float am_l[64];
  __shared__ float red[256];
  unsigned short* g_l = smem;                      // bytes [0,16K)
  unsigned short* mt  = smem + 8192;               // bytes [16K,48K)
  unsigned short* h_l = smem + 8192;
  float* mred = (float*)smem;                      // producer scratch [4][32][33]

  const f32x4 z = {0.f, 0.f, 0.f, 0.f};
  const unsigned ph = (unsigned)(t + 1);

  // load attention state early (independent of M)
  float att[4][4];
  {
    const f32x4* ag = (const f32x4*)(att_g + (size_t)blk * 4096 + tid * 16);
    #pragma unroll
    for (int n = 0; n < 4; n++) {
      f32x4 v4 = ag[n];
      #pragma unroll
      for (int v = 0; v < 4; v++) att[n][v] = v4[v];
    }
  }

  // ---- producers: ch<16 compute one 32x32 tile of M = siaT @ axonT^T ----
  if (ch < 16) {
    int d0 = (ch >> 2) * 32, e0 = (ch & 3) * 32;
    const unsigned short* ap0 = siaT_in + (size_t)(b * 128 + d0 + lr) * C + w * 544 + lg * 8;
    const unsigned short* ap1 = ap0 + (size_t)16 * C;
    const unsigned short* bp0 = axonT + (size_t)(b * E + e0 + lr) * C + w * 544 + lg * 8;
    const unsigned short* bp1 = bp0 + (size_t)16 * C;
    f32x4 a00 = z, a01 = z, a10 = z, a11 = z;
    #pragma unroll 4
    for (int kk = 0; kk < 17; kk++) {
      int k0 = kk * 32;
      s16x8 A0 = *(const s16x8*)(ap0 + k0);
      s16x8 A1 = *(const s16x8*)(ap1 + k0);
      s16x8 B0 = *(const s16x8*)(bp0 + k0);
      s16x8 B1 = *(const s16x8*)(bp1 + k0);
      a00 = __builtin_amdgcn_mfma_f32_16x16x32_bf16(A0, B0, a00, 0, 0, 0);
      a01 = __builtin_amdgcn_mfma_f32_16x16x32_bf16(A0, B1, a01, 0, 0, 0);
      a10 = __builtin_amdgcn_mfma_f32_16x16x32_bf16(A1, B0, a10, 0, 0, 0);
      a11 = __builtin_amdgcn_mfma_f32_16x16x32_bf16(A1, B1, a11, 0, 0, 0);
    }
    #pragma unroll
    for (int v = 0; v < 4; v++) {
      mred[(w * 32 + lg * 4 + v) * 33 + lr]           = a00[v];
      mred[(w * 32 + lg * 4 + v) * 33 + 16 + lr]      = a01[v];
      mred[(w * 32 + 16 + lg * 4 + v) * 33 + lr]      = a10[v];
      mred[(w * 32 + 16 + lg * 4 + v) * 33 + 16 + lr] = a11[v];
    }
    __syncthreads();
    {
      int r = tid >> 3, c = (tid & 7) * 4;
      float s0 = 0.f, s1 = 0.f, s2 = 0.f, s3 = 0.f;
      #pragma unroll
      for (int w4 = 0; w4 < 4; w4++) {
        const float* p = &mred[(w4 * 32 + r) * 33 + c];
        s0 += p[0]; s1 += p[1]; s2 += p[2]; s3 += p[3];
      }
      unsigned long long pk = (unsigned long long)f2b(s0)
                            | ((unsigned long long)f2b(s1) << 16)
                            | ((unsigned long long)f2b(s2) << 32)
                            | ((unsigned long long)f2b(s3) << 48);
      st_coh_u64(Mt64 + (((size_t)(b * 128 + d0 + r) * 128) + e0 + c) / 4, pk);
    }
    asm volatile("s_waitcnt vmcnt(0)" ::: "memory");
    __syncthreads();
    if (tid == 0) st_coh_u32(mflag + b * 16 + ch, ph);
  }
  // ---- all blocks: wait for this batch's 16 M-tiles ----
  if (tid < 16) {
    while (ld_coh_u32(mflag + b * 16 + tid) < ph) __builtin_amdgcn_s_sleep(1);
  }
  __syncthreads();
  // ---- stage Mt -> LDS (PLAIN cached loads; first touch misses to MALL) ----
  {
    const unsigned long long* mtp = Mt64 + (size_t)b * 4096;
    #pragma unroll
    for (int k = 0; k < 16; k++) {
      int idx = tid + k * 256;
      unsigned long long v = mtp[idx];
      int r = idx >> 5, c4 = (idx & 31) * 4;
      *(unsigned long long*)&mt[mtidx(r, c4)] = v;
    }
  }
  __syncthreads();
  // ---- phase A: g = dendron @ M / C ----
  {
    s16x8 afr[4];
    #pragma unroll
    for (int ke = 0; ke < 4; ke++)
      afr[ke] = *(const s16x8*)(dendron_bf + (size_t)(b * C + j0 + w * 16 + lr) * E + ke * 32 + lg * 8);
    #pragma unroll
    for (int n = 0; n < 8; n++) {
      f32x4 acc = z;
      #pragma unroll
      for (int ke = 0; ke < 4; ke++) {
        s16x8 bf = *(const s16x8*)&mt[mtidx(n * 16 + lr, ke * 32 + lg * 8)];
        acc = __builtin_amdgcn_mfma_f32_16x16x32_bf16(afr[ke], bf, acc, 0, 0, 0);
      }
      #pragma unroll
      for (int v = 0; v < 4; v++)
        g_l[gidx(w * 16 + lg * 4 + v, n * 16 + lr)] = f2b(acc[v] * (1.f / C));
    }
  }
  __syncthreads();
  // ---- phase B: h = relu(g @ w1^T + b1) ----
  {
    s16x8 gf[4];
    #pragma unroll
    for (int kd = 0; kd < 4; kd++)
      gf[kd] = *(const s16x8*)&g_l[gidx(w * 16 + lr, kd * 32 + lg * 8)];
    #pragma unroll
    for (int n = 0; n < 16; n++) {
      f32x4 acc = z;
      #pragma unroll
      for (int kd = 0; kd < 4; kd++) {
        s16x8 bf = *(const s16x8*)(w1_bf + (size_t)(n * 16 + lr) * E + kd * 32 + lg * 8);
        acc = __builtin_amdgcn_mfma_f32_16x16x32_bf16(gf[kd], bf, acc, 0, 0, 0);
      }
      float b1v = b1g[n * 16 + lr];
      #pragma unroll
      for (int v = 0; v < 4; v++)
        h_l[hidx(w * 16 + lg * 4 + v, n * 16 + lr)] = f2b(fmaxf(acc[v] + b1v, 0.f));
    }
  }
  __syncthreads();
  // ---- phase C: out = h @ w2^T ; update att ; hist ----
  {
    s16x8 hf[8];
    #pragma unroll
    for (int kk = 0; kk < 8; kk++)
      hf[kk] = *(const s16x8*)&h_l[hidx(w * 16 + lr, kk * 32 + lg * 8)];
    int op = prog_op[b * T + t];
    float insF = (op == 1) ? 1.f : 0.f, trF = (op == 2) ? 1.f : 0.f;
    float projv[4];
    #pragma unroll
    for (int v = 0; v < 4; v++)
      projv[v] = proj_all[(size_t)(t * B + b) * C + j0 + w * 16 + lg * 4 + v];
    #pragma unroll
    for (int n = 0; n < 4; n++) {
      f32x4 acc = z;
      #pragma unroll
      for (int kk = 0; kk < 8; kk++) {
        s16x8 bf = *(const s16x8*)(w2_bf + (size_t)(n * 16 + lr) * HD + kk * 32 + lg * 8);
        acc = __builtin_amdgcn_mfma_f32_16x16x32_bf16(hf[kk], bf, acc, 0, 0, 0);
      }
      int a = n * 16 + lr;
      float b2v = b2g[a];
      float meta_a = meta_all[(size_t)(t * B + b) * AD + a];
      #pragma unroll
      for (int v = 0; v < 4; v++) {
        int row = lg * 4 + v;
        int i = j0 + w * 16 + row;
        float transfer = acc[v] + b2v + b2f(g_l[gidx(w * 16 + row, 64 + a)]);
        float insert = meta_a * projv[v];
        float attv = att[n][v] + insF * insert + trF * transfer;
        attv = (attv >= 0.f) ? attv : 0.01f * attv;
        attv = fminf(fmaxf(attv, -1.f), 2.f);
        att[n][v] = attv;
        size_t hi = (((size_t)t * B + b) * C + i) * AD + a;
        __builtin_nontemporal_store(attv, att_hist + hi);
        __builtin_nontemporal_store(insert, ins_hist + hi);
        __builtin_nontemporal_store(transfer, trans_hist + hi);
      }
    }
  }
  // ---- epilogue: amean ----
  float amr[4];
  {
    float s[4];
    #pragma unroll
    for (int v = 0; v < 4; v++) s[v] = att[0][v] + att[1][v] + att[2][v] + att[3][v];
    #pragma unroll
    for (int v = 0; v < 4; v++) {
      s[v] += __shfl_xor(s[v], 1, 64);
      s[v] += __shfl_xor(s[v], 2, 64);
      s[v] += __shfl_xor(s[v], 4, 64);
      s[v] += __shfl_xor(s[v], 8, 64);
      amr[v] = s[v] * (1.f / AD);
    }
    if (lr == 0) {
      #pragma unroll
      for (int v = 0; v < 4; v++) am_l[w * 16 + lg * 4 + v] = amr[v];
    }
  }
  if (t < T - 1) {
    // persist att state + att-half of next siaT
    {
      f32x4* ag = (f32x4*)(att_g + (size_t)blk * 4096 + tid * 16);
      #pragma unroll
      for (int n = 0; n < 4; n++) {
        f32x4 v4;
        #pragma unroll
        for (int v = 0; v < 4; v++) v4[v] = att[n][v];
        ag[n] = v4;
        unsigned long long pk = 0;
        #pragma unroll
        for (int v = 0; v < 4; v++)
          pk |= (unsigned long long)f2b(att[n][v] * amr[v]) << (16 * v);
        *(unsigned long long*)(siaT_out + (size_t)(b * 128 + 64 + n * 16 + lr) * C + j0 + w * 16 + lg * 4) = pk;
      }
    }
    __syncthreads();   // am_l ready
    // id half of next siaT
    #pragma unroll
    for (int k2 = 0; k2 < 2; k2++) {
      int idx = tid + k2 * 256;
      int d = idx >> 3, part = idx & 7;
      int j = part * 8;
      s16x8 iv = *(const s16x8*)(idT_g + (size_t)(b * 64 + d) * C + j0 + j);
      s16x8 ov;
      #pragma unroll
      for (int m = 0; m < 8; m++)
        ov[m] = (short)f2b(b2f((unsigned short)iv[m]) * am_l[j + m]);
      *(s16x8*)(siaT_out + (size_t)(b * 128 + d) * C + j0 + j) = ov;
    }
  } else {
    // ---- last step: rowmean (coherent) + sflag + per-batch softmax tail ----
    if (lr == 0) {
      #pragma unroll
      for (int v = 0; v < 4; v++)
        st_coh_f32(rowmean + (size_t)b * C + j0 + w * 16 + lg * 4 + v, amr[v]);
    }
    asm volatile("s_waitcnt vmcnt(0)" ::: "memory");
    __syncthreads();
    if (tid == 0) st_coh_u32(sflag + b * 34 + ch, 1u);
    if (ch == 0) {
      if (tid < 34) {
        while (ld_coh_u32(sflag + b * 34 + tid) < 1u) __builtin_amdgcn_s_sleep(1);
      }
      __syncthreads();
      float* am = (float*)smem;
      for (int i = tid; i < C; i += 256) am[i] = rowmean[(size_t)b * C + i];
      __syncthreads();
      float mx = -1e30f;
      for (int i = tid; i < C; i += 256) mx = fmaxf(mx, am[i]);
      red[tid] = mx; __syncthreads();
      for (int s2 = 128; s2 > 0; s2 >>= 1) { if (tid < s2) red[tid] = fmaxf(red[tid], red[tid + s2]); __syncthreads(); }
      mx = red[0]; __syncthreads();
      float sm = 0.f;
      for (int i = tid; i < C; i += 256) sm += expf(am[i] - mx);
      red[tid] = sm; __syncthreads();
      for (int s2 = 128; s2 > 0; s2 >>= 1) { if (tid < s2) red[tid] += red[tid + s2]; __syncthreads(); }
      float lse = logf(red[0]) + mx;
      for (int i = tid; i < C; i += 256) out[(size_t)b * C + i] = am[i] - lse;
    }
  }
}

extern "C" void kernel_launch(void* const* d_in, const int* in_sizes, int n_in,
                              void* d_out, int out_size, void* d_ws, size_t ws_size,
                              hipStream_t stream) {
  const int* scene     = (const int*)d_in[0];
  const int* prog_op   = (const int*)d_in[1];
  const int* prog_arg  = (const int*)d_in[2];
  const float* aein    = (const float*)d_in[3];
  const float* aeout   = (const float*)d_in[4];
  const float* aeid    = (const float*)d_in[5];
  const float* cein    = (const float*)d_in[6];
  const float* ceout   = (const float*)d_in[7];
  const float* ceid    = (const float*)d_in[8];
  const float* att_init = (const float*)d_in[11];
  const float* aw1 = (const float*)d_in[12];
  const float* ab1 = (const float*)d_in[13];
  const float* aw2 = (const float*)d_in[14];
  const float* ab2 = (const float*)d_in[15];
  const float* mw1 = (const float*)d_in[16];
  const float* mb1 = (const float*)d_in[17];
  const float* mw2 = (const float*)d_in[18];
  const float* mb2 = (const float*)d_in[19];

  char* ws = (char*)d_ws;
  size_t off = 0;
  auto carve = [&](size_t bytes) { char* p = ws + off; off += (bytes + 255) & ~(size_t)255; return p; };
  float* proj_all  = (float*)carve((size_t)T * B * C * 4);
  float* meta_all  = (float*)carve((size_t)T * B * AD * 4);
  float* mw1T      = (float*)carve((size_t)192 * HD * 4);
  float* mw2T      = (float*)carve((size_t)HD * AD * 4);
  float* rowmean   = (float*)carve((size_t)B * C * 4);
  float* att_g     = (float*)carve((size_t)272 * 4096 * 4);
  unsigned short* dendron_bf = (unsigned short*)carve((size_t)B * C * E * 2);
  unsigned short* axonT      = (unsigned short*)carve((size_t)B * E * C * 2);
  unsigned short* idT_g      = (unsigned short*)carve((size_t)B * 64 * C * 2);
  unsigned short* siaT       = (unsigned short*)carve((size_t)B * 128 * C * 2);
  unsigned long long* Mt64   = (unsigned long long*)carve((size_t)B * 4096 * 8);
  unsigned short* w1_bf      = (unsigned short*)carve((size_t)HD * E * 2);
  unsigned short* w2_bf      = (unsigned short*)carve((size_t)AD * HD * 2);
  unsigned*       flags      = (unsigned*)carve(2048);
  unsigned*       mflag = flags;            // [8][16]
  unsigned*       sflag = flags + 128;      // [8][34]

  float* out_sm     = (float*)d_out;
  float* att_hist   = out_sm + B * C;
  float* ins_hist   = att_hist + (size_t)T * B * C * AD;
  float* trans_hist = ins_hist + (size_t)T * B * C * AD;

  k_setupA<<<dim3(4545), dim3(256), 0, stream>>>(scene, aein, cein, aw1, aw2, mw1, mw2,
                                                 dendron_bf, w1_bf, w2_bf, mw1T, mw2T, flags);
  k_setupB<<<dim3(280), dim3(256), 0, stream>>>(scene, aeout, aeid, ceout, ceid, att_init,
                                                prog_op, prog_arg, mw1T, mb1, mw2T, mb2,
                                                axonT, idT_g, siaT, att_g,
                                                meta_all, proj_all);
  for (int t = 0; t < T; t++) {
    k_step<<<dim3(272), dim3(256), 0, stream>>>(t, dendron_bf, axonT, idT_g, siaT,
                                                w1_bf, ab1, w2_bf, ab2,
                                                proj_all, meta_all, prog_op,
                                                Mt64, att_g, siaT, rowmean, out_sm,
                                                att_hist, ins_hist, trans_hist,
                                                mflag, sflag);
  }
}